// Round 1
// baseline (941.911 us; speedup 1.0000x reference)
//
#include <hip/hip_runtime.h>
#include <hip/hip_bf16.h>
#include <cstddef>

using u16 = unsigned short;
using short8 = __attribute__((ext_vector_type(8))) short;
using f32x4 = __attribute__((ext_vector_type(4))) float;

constexpr int B_   = 8192;
constexpr int IN_  = 256;
constexpr int COND_= 1024;
constexpr int H_   = 1024;
constexpr int LAT_ = 128;
constexpr int NE_  = 6;
constexpr int GH_  = 64;
constexpr int INP_ = 1152;   // LAT+COND == LAT+H
constexpr int K0_  = 1536;   // IN+COND+IN
constexpr int K1_  = 1280;   // H+IN

constexpr int BM = 128, BN = 128, BK = 64, LDT = BK + 8; // 144B LDS row stride

__device__ __forceinline__ u16 f2b(float f) {
  __hip_bfloat16 h = __float2bfloat16(f);
  return *reinterpret_cast<u16*>(&h);
}
__device__ __forceinline__ float elu1(float x) { return x > 0.f ? x : (__expf(x) - 1.f); }

// ---------------- transpose + f32->bf16 convert: in [R][C] f32 -> out [C][R] bf16
__global__ void k_transpose(const float* __restrict__ in, u16* __restrict__ out,
                            int R, int C, long inStride, long outStride) {
  __shared__ float t[32][33];
  const float* ip = in + (long)blockIdx.z * inStride;
  u16* op = out + (long)blockIdx.z * outStride;
  int c0 = blockIdx.x * 32, r0 = blockIdx.y * 32;
  int tx = threadIdx.x, ty = threadIdx.y; // 32x8
#pragma unroll
  for (int i = 0; i < 4; i++) {
    int r = r0 + ty + i * 8, c = c0 + tx;
    if (r < R && c < C) t[ty + i * 8][tx] = ip[(long)r * C + c];
  }
  __syncthreads();
#pragma unroll
  for (int i = 0; i < 4; i++) {
    int c = c0 + ty + i * 8, r = r0 + tx;
    if (r < R && c < C) op[(long)c * R + r] = f2b(t[tx][ty + i * 8]);
  }
}

// ---------------- build A0 = [x|y|x] bf16 and A1 x-columns
__global__ void k_prep(const float* __restrict__ x, const float* __restrict__ y,
                       u16* __restrict__ A0, u16* __restrict__ A1) {
  long idx = (long)blockIdx.x * blockDim.x + threadIdx.x;
  long n0 = (long)B_ * K0_;
  if (idx < n0) {
    int b = (int)(idx / K0_), c = (int)(idx % K0_);
    float v;
    if (c < IN_)            v = x[(long)b * IN_ + c];
    else if (c < IN_+COND_) v = y[(long)b * COND_ + (c - IN_)];
    else                    v = x[(long)b * IN_ + (c - IN_ - COND_)];
    A0[idx] = f2b(v);
  } else {
    long j = idx - n0;
    if (j < (long)B_ * IN_) {
      int b = (int)(j / IN_), c = (int)(j % IN_);
      A1[(long)b * K1_ + H_ + c] = f2b(x[(long)b * IN_ + c]);
    }
  }
}

// ---------------- z = mu + eps*exp(0.5*lv); fill ZY=[z|y], z-cols of D1,D2
__global__ void k_z(const float* __restrict__ mu, const float* __restrict__ lv,
                    const float* __restrict__ eps, const float* __restrict__ y,
                    u16* __restrict__ ZY, u16* __restrict__ D1, u16* __restrict__ D2) {
  long idx = (long)blockIdx.x * blockDim.x + threadIdx.x;
  if (idx >= (long)B_ * INP_) return;
  int b = (int)(idx / INP_), c = (int)(idx % INP_);
  if (c < LAT_) {
    long o = (long)b * LAT_ + c;
    float z = mu[o] + eps[o] * __expf(0.5f * lv[o]);
    u16 zb = f2b(z);
    ZY[idx] = zb; D1[idx] = zb; D2[idx] = zb;
  } else {
    ZY[idx] = f2b(y[(long)b * COND_ + (c - LAT_)]);
  }
}

// ---------------- gating tail: g2 = elu(g1@w1+b1); logits = g2@w2+b2; softmax
__global__ __launch_bounds__(256) void k_gate(const float* __restrict__ G1,
    const float* __restrict__ w1, const float* __restrict__ b1,
    const float* __restrict__ w2, const float* __restrict__ b2,
    float* __restrict__ coeff) {
  __shared__ float W1[64][65];
  __shared__ float W2[64][8];
  __shared__ float B1[64], B2[8];
  int tid = threadIdx.x;
  for (int i = tid; i < 64 * 64; i += 256) W1[i >> 6][i & 63] = w1[i];
  for (int i = tid; i < 64 * 6; i += 256) W2[i / 6][i % 6] = w2[i];
  if (tid < 64) B1[tid] = b1[tid];
  if (tid < 8)  B2[tid] = (tid < 6) ? b2[tid] : 0.f;
  __syncthreads();
  int row = blockIdx.x * 256 + tid;
  const float* gr = G1 + (long)row * GH_;
  float g[64];
#pragma unroll
  for (int i = 0; i < 16; i++) {
    float4 v = *(const float4*)(gr + i * 4);
    g[i*4] = v.x; g[i*4+1] = v.y; g[i*4+2] = v.z; g[i*4+3] = v.w;
  }
  float lg[6];
#pragma unroll
  for (int e = 0; e < 6; e++) lg[e] = B2[e];
  for (int n = 0; n < 64; n++) {
    float s = B1[n];
#pragma unroll
    for (int k = 0; k < 64; k++) s += g[k] * W1[k][n];
    s = elu1(s);
#pragma unroll
    for (int e = 0; e < 6; e++) lg[e] += s * W2[n][e];
  }
  float m = lg[0];
#pragma unroll
  for (int e = 1; e < 6; e++) m = fmaxf(m, lg[e]);
  float p[6], sum = 0.f;
#pragma unroll
  for (int e = 0; e < 6; e++) { p[e] = __expf(lg[e] - m); sum += p[e]; }
  float inv = 1.f / sum;
#pragma unroll
  for (int e = 0; e < 6; e++) coeff[(long)row * 6 + e] = p[e] * inv;
}

// ---------------- generic MFMA GEMM (+MoE): out = act( sum_e c_e*(A@W_e^T) + bias )
// WT: [E][N][K] bf16 (pre-transposed). coeff: [M][6] or null (then E==1, c=1).
// Output: bf16 (outH,ldo) OR f32 split (outF cols<splitcol, outF2 rest).
__global__ __launch_bounds__(256, 2) void k_gemm(
    const u16* __restrict__ A, int lda,
    const u16* __restrict__ WT, long wstride,
    const float* __restrict__ bias,
    const float* __restrict__ coeff,
    int N, int K, int E,
    u16* __restrict__ outH, float* __restrict__ outF, float* __restrict__ outF2,
    int ldo, int splitcol, const float* __restrict__ bias2, int act)
{
  __shared__ __align__(16) u16 As[BM][LDT];
  __shared__ __align__(16) u16 Bs[BN][LDT];
  __shared__ float Cf[BM][8];

  int tid = threadIdx.x;
  int lane = tid & 63, wid = tid >> 6;
  int wr = wid >> 1, wc = wid & 1;
  int brow = blockIdx.x * BM, bcol = blockIdx.y * BN;
  int lr = lane & 15, hi = lane >> 4;
  int lk = hi * 8;

  if (coeff && tid < BM) {
#pragma unroll
    for (int e = 0; e < 8; e++)
      Cf[tid][e] = (e < 6) ? coeff[(long)(brow + tid) * 6 + e] : 0.f;
  }

  f32x4 acc[4][4];
#pragma unroll
  for (int m = 0; m < 4; m++)
#pragma unroll
    for (int n = 0; n < 4; n++)
#pragma unroll
      for (int r = 0; r < 4; r++) acc[m][n][r] = 0.f;

  int sr = tid >> 1, sc = (tid & 1) * 32;
  const u16* Arow = A + (long)(brow + sr) * lda + sc;
  bool bvalid = (bcol + sr) < N;

  for (int e = 0; e < E; e++) {
    const u16* Brow = WT + (long)e * wstride + (long)(bcol + sr) * K + sc;
    f32x4 pacc[4][4];
#pragma unroll
    for (int m = 0; m < 4; m++)
#pragma unroll
      for (int n = 0; n < 4; n++)
#pragma unroll
        for (int r = 0; r < 4; r++) pacc[m][n][r] = 0.f;

    for (int kt = 0; kt < K; kt += BK) {
      __syncthreads();
#pragma unroll
      for (int i = 0; i < 4; i++) {
        int4 va = *(const int4*)(Arow + kt + i * 8);
        *(int4*)&As[sr][sc + i * 8] = va;
      }
#pragma unroll
      for (int i = 0; i < 4; i++) {
        int4 vb = make_int4(0, 0, 0, 0);
        if (bvalid) vb = *(const int4*)(Brow + kt + i * 8);
        *(int4*)&Bs[sr][sc + i * 8] = vb;
      }
      __syncthreads();
#pragma unroll
      for (int kk = 0; kk < BK; kk += 32) {
        short8 af[4], bfr[4];
#pragma unroll
        for (int m = 0; m < 4; m++) af[m]  = *(const short8*)&As[wr * 64 + m * 16 + lr][kk + lk];
#pragma unroll
        for (int n = 0; n < 4; n++) bfr[n] = *(const short8*)&Bs[wc * 64 + n * 16 + lr][kk + lk];
#pragma unroll
        for (int m = 0; m < 4; m++)
#pragma unroll
          for (int n = 0; n < 4; n++)
            pacc[m][n] = __builtin_amdgcn_mfma_f32_16x16x32_bf16(af[m], bfr[n], pacc[m][n], 0, 0, 0);
      }
    }
    if (coeff) {
#pragma unroll
      for (int m = 0; m < 4; m++)
#pragma unroll
        for (int r = 0; r < 4; r++) {
          float c = Cf[wr * 64 + m * 16 + hi * 4 + r][e];
#pragma unroll
          for (int n = 0; n < 4; n++) acc[m][n][r] += c * pacc[m][n][r];
        }
    } else {
#pragma unroll
      for (int m = 0; m < 4; m++)
#pragma unroll
        for (int n = 0; n < 4; n++) acc[m][n] += pacc[m][n];
    }
  }

  // epilogue
#pragma unroll
  for (int m = 0; m < 4; m++)
#pragma unroll
    for (int n = 0; n < 4; n++) {
      int col = bcol + wc * 64 + n * 16 + lr;
      if (col >= N) continue;
#pragma unroll
      for (int r = 0; r < 4; r++) {
        int rowl = wr * 64 + m * 16 + hi * 4 + r;
        long row = brow + rowl;
        float v = acc[m][n][r];
        if (coeff) {
          float bv = 0.f;
#pragma unroll
          for (int e = 0; e < 6; e++) bv += Cf[rowl][e] * bias[(long)e * N + col];
          v += bv;
        } else {
          v += (col < splitcol) ? bias[col] : bias2[col - splitcol];
        }
        if (act) v = elu1(v);
        if (outH) outH[row * ldo + col] = f2b(v);
        else if (col < splitcol) outF[row * ldo + col] = v;
        else outF2[row * ldo + (col - splitcol)] = v;
      }
    }
}

extern "C" void kernel_launch(void* const* d_in, const int* in_sizes, int n_in,
                              void* d_out, int out_size, void* d_ws, size_t ws_size,
                              hipStream_t stream) {
  (void)in_sizes; (void)out_size;
  if (n_in < 23) return;
  const float* x      = (const float*)d_in[0];
  const float* y      = (const float*)d_in[1];
  const float* eps    = (const float*)d_in[2];
  const float* enc_w0 = (const float*)d_in[3];
  const float* enc_b0 = (const float*)d_in[4];
  const float* enc_w1 = (const float*)d_in[5];
  const float* enc_b1 = (const float*)d_in[6];
  const float* mu_w   = (const float*)d_in[7];
  const float* mu_b   = (const float*)d_in[8];
  const float* lv_w   = (const float*)d_in[9];
  const float* lv_b   = (const float*)d_in[10];
  const float* g_w0   = (const float*)d_in[11];
  const float* g_b0   = (const float*)d_in[12];
  const float* g_w1   = (const float*)d_in[13];
  const float* g_b1   = (const float*)d_in[14];
  const float* g_w2   = (const float*)d_in[15];
  const float* g_b2   = (const float*)d_in[16];
  const float* exp_w0 = (const float*)d_in[17];
  const float* exp_b0 = (const float*)d_in[18];
  const float* exp_w1 = (const float*)d_in[19];
  const float* exp_b1 = (const float*)d_in[20];
  const float* exp_w2 = (const float*)d_in[21];
  const float* exp_b2 = (const float*)d_in[22];

  char* ws = (char*)d_ws;
  size_t off = 0;
  auto alloc = [&](size_t bytes) -> void* {
    void* p = ws + off; off += (bytes + 255) & ~(size_t)255; return p;
  };
  u16* A0     = (u16*)alloc((size_t)B_ * K0_ * 2);        // enc0 input [x|y|x]; later D1
  u16* A1     = (u16*)alloc((size_t)B_ * K1_ * 2);        // enc1 input [h1|x]; later D2
  u16* H2     = (u16*)alloc((size_t)B_ * H_ * 2);         // enc2 output; later G1/COEFF/ew2T
  u16* ZY     = (u16*)alloc((size_t)B_ * INP_ * 2);       // [z|y]; later ew1T
  u16* encw0T = (u16*)alloc((size_t)K0_ * H_ * 2);
  u16* encw1T = (u16*)alloc((size_t)K1_ * H_ * 2);
  u16* mulvT  = (u16*)alloc((size_t)256 * H_ * 2);
  u16* gw0T   = (u16*)alloc((size_t)GH_ * INP_ * 2);
  u16* ew0T   = (u16*)alloc((size_t)NE_ * H_ * INP_ * 2);
  if (ws_size < off) return;

  // aliases (lifetime-checked):
  u16* D1 = A0;                                  // A0 dead after enc0
  u16* D2 = A1;                                  // A1 dead after enc1
  float* G1    = (float*)H2;                     // H2 dead after mu/lv
  float* COEFF = (float*)((char*)H2 + (size_t)B_ * GH_ * 4);
  u16* ew2T = (u16*)((char*)H2 + (size_t)4 * 1024 * 1024);   // transposed after mu/lv
  u16* ew1T = ZY;                                            // transposed after moe0

  float* outO = (float*)d_out;                       // [B,256]
  float* muO  = outO + (size_t)B_ * IN_;             // [B,128]
  float* lvO  = muO + (size_t)B_ * LAT_;             // [B,128]

  dim3 tb(32, 8);
  // weight transposes needed before the encoder/gating/moe0
  k_transpose<<<dim3(32, 48), tb, 0, stream>>>(enc_w0, encw0T, K0_, H_, 0, 0);
  k_transpose<<<dim3(32, 40), tb, 0, stream>>>(enc_w1, encw1T, K1_, H_, 0, 0);
  k_transpose<<<dim3(4, 32),  tb, 0, stream>>>(mu_w, mulvT, H_, LAT_, 0, 0);
  k_transpose<<<dim3(4, 32),  tb, 0, stream>>>(lv_w, mulvT + (size_t)LAT_ * H_, H_, LAT_, 0, 0);
  k_transpose<<<dim3(2, 36),  tb, 0, stream>>>(g_w0, gw0T, INP_, GH_, 0, 0);
  k_transpose<<<dim3(32, 36, NE_), tb, 0, stream>>>(exp_w0, ew0T, INP_, H_,
                                                    (long)INP_ * H_, (long)INP_ * H_);
  // concat buffers
  long npr = (long)B_ * K0_ + (long)B_ * IN_;
  k_prep<<<(int)((npr + 255) / 256), 256, 0, stream>>>(x, y, A0, A1);

  // encoder
  k_gemm<<<dim3(B_ / BM, H_ / BN), 256, 0, stream>>>(A0, K0_, encw0T, 0, enc_b0, nullptr,
      H_, K0_, 1, A1, nullptr, nullptr, K1_, H_, nullptr, 1);
  k_gemm<<<dim3(B_ / BM, H_ / BN), 256, 0, stream>>>(A1, K1_, encw1T, 0, enc_b1, nullptr,
      H_, K1_, 1, H2, nullptr, nullptr, H_, H_, nullptr, 1);
  // mu / logvar (split f32 outputs straight into d_out)
  k_gemm<<<dim3(B_ / BM, 2), 256, 0, stream>>>(H2, H_, mulvT, 0, mu_b, nullptr,
      256, H_, 1, nullptr, muO, lvO, LAT_, LAT_, lv_b, 0);

  // exp_w2 transpose into freed H2 space (after mu/lv read H2)
  k_transpose<<<dim3(8, 36, NE_), tb, 0, stream>>>(exp_w2, ew2T, INP_, IN_,
                                                   (long)INP_ * IN_, (long)INP_ * IN_);
  // z + [z|y] assembly
  long nz = (long)B_ * INP_;
  k_z<<<(int)((nz + 255) / 256), 256, 0, stream>>>(muO, lvO, eps, y, ZY, D1, D2);

  // gating
  k_gemm<<<dim3(B_ / BM, 1), 256, 0, stream>>>(ZY, INP_, gw0T, 0, g_b0, nullptr,
      GH_, INP_, 1, nullptr, G1, nullptr, GH_, GH_, nullptr, 1);
  k_gate<<<B_ / 256, 256, 0, stream>>>(G1, g_w1, g_b1, g_w2, g_b2, COEFF);

  // decoder MoE layer 0: ZY -> D1[:,128:1152]
  k_gemm<<<dim3(B_ / BM, H_ / BN), 256, 0, stream>>>(ZY, INP_, ew0T, (long)H_ * INP_,
      exp_b0, COEFF, H_, INP_, NE_, D1 + LAT_, nullptr, nullptr, INP_, H_, nullptr, 1);
  // exp_w1 transpose into freed ZY space (after moe0 read ZY)
  k_transpose<<<dim3(32, 36, NE_), tb, 0, stream>>>(exp_w1, ew1T, INP_, H_,
                                                    (long)INP_ * H_, (long)INP_ * H_);
  // decoder MoE layer 1: D1 -> D2[:,128:1152]
  k_gemm<<<dim3(B_ / BM, H_ / BN), 256, 0, stream>>>(D1, INP_, ew1T, (long)H_ * INP_,
      exp_b1, COEFF, H_, INP_, NE_, D2 + LAT_, nullptr, nullptr, INP_, H_, nullptr, 1);
  // decoder MoE layer 2: D2 -> d_out [B,256] f32
  k_gemm<<<dim3(B_ / BM, 2), 256, 0, stream>>>(D2, INP_, ew2T, (long)IN_ * INP_,
      exp_b2, COEFF, IN_, INP_, NE_, nullptr, outO, nullptr, IN_, IN_, nullptr, 0);
}

// Round 2
// 722.273 us; speedup vs baseline: 1.3041x; 1.3041x over previous
//
#include <hip/hip_runtime.h>
#include <hip/hip_bf16.h>
#include <cstddef>

using u16 = unsigned short;
using short8 = __attribute__((ext_vector_type(8))) short;
using f32x4 = __attribute__((ext_vector_type(4))) float;

constexpr int B_   = 8192;
constexpr int IN_  = 256;
constexpr int COND_= 1024;
constexpr int H_   = 1024;
constexpr int LAT_ = 128;
constexpr int NE_  = 6;
constexpr int GH_  = 64;
constexpr int INP_ = 1152;   // LAT+COND == LAT+H
constexpr int K0_  = 1536;   // IN+COND+IN
constexpr int K1_  = 1280;   // H+IN

constexpr int BK = 64;       // K-step (128 B per LDS row, linear, no pad)

typedef const __attribute__((address_space(1))) void gv_t;
typedef __attribute__((address_space(3))) void lv_t;
#define GLDS(g, l) __builtin_amdgcn_global_load_lds((gv_t*)(g), (lv_t*)(l), 16, 0, 0)

__device__ __forceinline__ u16 f2b(float f) {
  __hip_bfloat16 h = __float2bfloat16(f);
  return *reinterpret_cast<u16*>(&h);
}
__device__ __forceinline__ float elu1(float x) { return x > 0.f ? x : (__expf(x) - 1.f); }

// ---------------- transpose + f32->bf16 convert: in [R][C] f32 -> out [C][R] bf16
__global__ void k_transpose(const float* __restrict__ in, u16* __restrict__ out,
                            int R, int C, long inStride, long outStride) {
  __shared__ float t[32][33];
  const float* ip = in + (long)blockIdx.z * inStride;
  u16* op = out + (long)blockIdx.z * outStride;
  int c0 = blockIdx.x * 32, r0 = blockIdx.y * 32;
  int tx = threadIdx.x, ty = threadIdx.y; // 32x8
#pragma unroll
  for (int i = 0; i < 4; i++) {
    int r = r0 + ty + i * 8, c = c0 + tx;
    if (r < R && c < C) t[ty + i * 8][tx] = ip[(long)r * C + c];
  }
  __syncthreads();
#pragma unroll
  for (int i = 0; i < 4; i++) {
    int c = c0 + ty + i * 8, r = r0 + tx;
    if (r < R && c < C) op[(long)c * R + r] = f2b(t[tx][ty + i * 8]);
  }
}

// ---------------- build A0 = [x|y|x] bf16 and A1 x-columns
__global__ void k_prep(const float* __restrict__ x, const float* __restrict__ y,
                       u16* __restrict__ A0, u16* __restrict__ A1) {
  long idx = (long)blockIdx.x * blockDim.x + threadIdx.x;
  long n0 = (long)B_ * K0_;
  if (idx < n0) {
    int b = (int)(idx / K0_), c = (int)(idx % K0_);
    float v;
    if (c < IN_)            v = x[(long)b * IN_ + c];
    else if (c < IN_+COND_) v = y[(long)b * COND_ + (c - IN_)];
    else                    v = x[(long)b * IN_ + (c - IN_ - COND_)];
    A0[idx] = f2b(v);
  } else {
    long j = idx - n0;
    if (j < (long)B_ * IN_) {
      int b = (int)(j / IN_), c = (int)(j % IN_);
      A1[(long)b * K1_ + H_ + c] = f2b(x[(long)b * IN_ + c]);
    }
  }
}

// ---------------- z = mu + eps*exp(0.5*lv); fill ZY=[z|y], z-cols of D1,D2
__global__ void k_z(const float* __restrict__ mu, const float* __restrict__ lv,
                    const float* __restrict__ eps, const float* __restrict__ y,
                    u16* __restrict__ ZY, u16* __restrict__ D1, u16* __restrict__ D2) {
  long idx = (long)blockIdx.x * blockDim.x + threadIdx.x;
  if (idx >= (long)B_ * INP_) return;
  int b = (int)(idx / INP_), c = (int)(idx % INP_);
  if (c < LAT_) {
    long o = (long)b * LAT_ + c;
    float z = mu[o] + eps[o] * __expf(0.5f * lv[o]);
    u16 zb = f2b(z);
    ZY[idx] = zb; D1[idx] = zb; D2[idx] = zb;
  } else {
    ZY[idx] = f2b(y[(long)b * COND_ + (c - LAT_)]);
  }
}

// ---------------- gating tail: g2 = elu(g1@w1+b1); logits = g2@w2+b2; softmax
__global__ __launch_bounds__(256) void k_gate(const float* __restrict__ G1,
    const float* __restrict__ w1, const float* __restrict__ b1,
    const float* __restrict__ w2, const float* __restrict__ b2,
    float* __restrict__ coeff) {
  __shared__ float W1[64][65];
  __shared__ float W2[64][8];
  __shared__ float B1[64], B2[8];
  int tid = threadIdx.x;
  for (int i = tid; i < 64 * 64; i += 256) W1[i >> 6][i & 63] = w1[i];
  for (int i = tid; i < 64 * 6; i += 256) W2[i / 6][i % 6] = w2[i];
  if (tid < 64) B1[tid] = b1[tid];
  if (tid < 8)  B2[tid] = (tid < 6) ? b2[tid] : 0.f;
  __syncthreads();
  int row = blockIdx.x * 256 + tid;
  const float* gr = G1 + (long)row * GH_;
  float g[64];
#pragma unroll
  for (int i = 0; i < 16; i++) {
    float4 v = *(const float4*)(gr + i * 4);
    g[i*4] = v.x; g[i*4+1] = v.y; g[i*4+2] = v.z; g[i*4+3] = v.w;
  }
  float lg[6];
#pragma unroll
  for (int e = 0; e < 6; e++) lg[e] = B2[e];
  for (int n = 0; n < 64; n++) {
    float s = B1[n];
#pragma unroll
    for (int k = 0; k < 64; k++) s += g[k] * W1[k][n];
    s = elu1(s);
#pragma unroll
    for (int e = 0; e < 6; e++) lg[e] += s * W2[n][e];
  }
  float m = lg[0];
#pragma unroll
  for (int e = 1; e < 6; e++) m = fmaxf(m, lg[e]);
  float p[6], sum = 0.f;
#pragma unroll
  for (int e = 0; e < 6; e++) { p[e] = __expf(lg[e] - m); sum += p[e]; }
  float inv = 1.f / sum;
#pragma unroll
  for (int e = 0; e < 6; e++) coeff[(long)row * 6 + e] = p[e] * inv;
}

// ---------------- MFMA GEMM (+MoE), m97 structure:
// linear LDS [BM][64], global_load_lds width-16 staging, ds_read_b128 frags.
// WT: [E][N][K] bf16 (pre-transposed). coeff: [M][6] when MOE.
// BM = 32*MREP, BN = 128 fixed. 4 waves, per-wave (16*MREP) x 64 output.
template<int MREP, bool MOE>
__global__ __launch_bounds__(256, 2) void k_gemm(
    const u16* __restrict__ A, int lda,
    const u16* __restrict__ WT, long wstride,
    const float* __restrict__ bias,
    const float* __restrict__ coeff,
    int N, int K, int E,
    u16* __restrict__ outH, float* __restrict__ outF, float* __restrict__ outF2,
    int ldo, int splitcol, const float* __restrict__ bias2, int act)
{
  constexpr int BMt = 32 * MREP;
  __shared__ __align__(16) u16 As[BMt][BK];   // linear: global_load_lds dest
  __shared__ __align__(16) u16 Bs[128][BK];
  __shared__ float Cf[BMt][8];

  const int tid = threadIdx.x;
  const int lane = tid & 63, w = tid >> 6;
  const int wr = w >> 1, wc = w & 1;
  const int brow = blockIdx.x * BMt, bcol = blockIdx.y * 128;
  const int lr = lane & 15, hi = lane >> 4;
  const int lk = hi * 8;

  if (MOE && tid < BMt) {
#pragma unroll
    for (int e2 = 0; e2 < 8; e2++)
      Cf[tid][e2] = (e2 < 6) ? coeff[(long)(brow + tid) * 6 + e2] : 0.f;
  }

  f32x4 acc[MREP][4];
#pragma unroll
  for (int m = 0; m < MREP; m++)
#pragma unroll
    for (int n = 0; n < 4; n++)
#pragma unroll
      for (int r = 0; r < 4; r++) acc[m][n][r] = 0.f;

  // staging geometry: one GLDS per wave covers 8 rows (64 lanes x 16 B = 1 KB);
  // 4 waves cover a 32-row chunk. lane l -> row +(l>>3), col elems (l&7)*8.
  const int srow = w * 8 + (lane >> 3);
  const int scol = (lane & 7) * 8;
  const u16* Asrc = A + (long)(brow + srow) * lda + scol;
  const u16* Bsrc0 = WT + (long)(bcol + srow) * K + scol;

  for (int e = 0; e < E; e++) {
    const u16* Bsrc = Bsrc0 + (long)e * wstride;
    f32x4 pacc[MREP][4];
    if constexpr (MOE) {
#pragma unroll
      for (int m = 0; m < MREP; m++)
#pragma unroll
        for (int n = 0; n < 4; n++)
#pragma unroll
          for (int r = 0; r < 4; r++) pacc[m][n][r] = 0.f;
    }

    for (int kt = 0; kt < K; kt += BK) {
      __syncthreads();                       // prev compute done before overwrite
#pragma unroll
      for (int i = 0; i < BMt / 32; i++)
        GLDS(Asrc + (long)(i * 32) * lda + kt, &As[i * 32 + srow][scol]);
#pragma unroll
      for (int i = 0; i < 4; i++)
        GLDS(Bsrc + (long)(i * 32) * K + kt, &Bs[i * 32 + srow][scol]);
      __syncthreads();                       // drains vmcnt (compiler-inserted)
#pragma unroll
      for (int kk = 0; kk < BK; kk += 32) {
        short8 af[MREP], bfr[4];
#pragma unroll
        for (int m = 0; m < MREP; m++)
          af[m] = *(const short8*)&As[wr * (16 * MREP) + m * 16 + lr][kk + lk];
#pragma unroll
        for (int n = 0; n < 4; n++)
          bfr[n] = *(const short8*)&Bs[wc * 64 + n * 16 + lr][kk + lk];
#pragma unroll
        for (int m = 0; m < MREP; m++)
#pragma unroll
          for (int n = 0; n < 4; n++) {
            if constexpr (MOE)
              pacc[m][n] = __builtin_amdgcn_mfma_f32_16x16x32_bf16(af[m], bfr[n], pacc[m][n], 0, 0, 0);
            else
              acc[m][n] = __builtin_amdgcn_mfma_f32_16x16x32_bf16(af[m], bfr[n], acc[m][n], 0, 0, 0);
          }
      }
    }
    if constexpr (MOE) {
#pragma unroll
      for (int m = 0; m < MREP; m++)
#pragma unroll
        for (int r = 0; r < 4; r++) {
          float c = Cf[wr * (16 * MREP) + m * 16 + hi * 4 + r][e];
#pragma unroll
          for (int n = 0; n < 4; n++) acc[m][n][r] += c * pacc[m][n][r];
        }
    }
  }

  // epilogue
#pragma unroll
  for (int m = 0; m < MREP; m++)
#pragma unroll
    for (int n = 0; n < 4; n++) {
      int col = bcol + wc * 64 + n * 16 + lr;
      if (col >= N) continue;
#pragma unroll
      for (int r = 0; r < 4; r++) {
        int rowl = wr * (16 * MREP) + m * 16 + hi * 4 + r;
        long row = brow + rowl;
        float v = acc[m][n][r];
        if constexpr (MOE) {
          float bv = 0.f;
#pragma unroll
          for (int e = 0; e < 6; e++) bv += Cf[rowl][e] * bias[(long)e * N + col];
          v += bv;
        } else {
          v += (col < splitcol) ? bias[col] : bias2[col - splitcol];
        }
        if (act) v = elu1(v);
        if (outH) outH[row * ldo + col] = f2b(v);
        else if (col < splitcol) outF[row * ldo + col] = v;
        else outF2[row * ldo + (col - splitcol)] = v;
      }
    }
}

extern "C" void kernel_launch(void* const* d_in, const int* in_sizes, int n_in,
                              void* d_out, int out_size, void* d_ws, size_t ws_size,
                              hipStream_t stream) {
  (void)in_sizes; (void)out_size;
  if (n_in < 23) return;
  const float* x      = (const float*)d_in[0];
  const float* y      = (const float*)d_in[1];
  const float* eps    = (const float*)d_in[2];
  const float* enc_w0 = (const float*)d_in[3];
  const float* enc_b0 = (const float*)d_in[4];
  const float* enc_w1 = (const float*)d_in[5];
  const float* enc_b1 = (const float*)d_in[6];
  const float* mu_w   = (const float*)d_in[7];
  const float* mu_b   = (const float*)d_in[8];
  const float* lv_w   = (const float*)d_in[9];
  const float* lv_b   = (const float*)d_in[10];
  const float* g_w0   = (const float*)d_in[11];
  const float* g_b0   = (const float*)d_in[12];
  const float* g_w1   = (const float*)d_in[13];
  const float* g_b1   = (const float*)d_in[14];
  const float* g_w2   = (const float*)d_in[15];
  const float* g_b2   = (const float*)d_in[16];
  const float* exp_w0 = (const float*)d_in[17];
  const float* exp_b0 = (const float*)d_in[18];
  const float* exp_w1 = (const float*)d_in[19];
  const float* exp_b1 = (const float*)d_in[20];
  const float* exp_w2 = (const float*)d_in[21];
  const float* exp_b2 = (const float*)d_in[22];

  char* ws = (char*)d_ws;
  size_t off = 0;
  auto alloc = [&](size_t bytes) -> void* {
    void* p = ws + off; off += (bytes + 255) & ~(size_t)255; return p;
  };
  u16* A0     = (u16*)alloc((size_t)B_ * K0_ * 2);        // enc0 input [x|y|x]; later D1
  u16* A1     = (u16*)alloc((size_t)B_ * K1_ * 2);        // enc1 input [h1|x]; later D2
  u16* H2     = (u16*)alloc((size_t)B_ * H_ * 2);         // enc2 output; later G1/COEFF/ew2T
  u16* ZY     = (u16*)alloc((size_t)B_ * INP_ * 2);       // [z|y]; later ew1T
  u16* encw0T = (u16*)alloc((size_t)K0_ * H_ * 2);
  u16* encw1T = (u16*)alloc((size_t)K1_ * H_ * 2);
  u16* mulvT  = (u16*)alloc((size_t)256 * H_ * 2);
  u16* gw0T   = (u16*)alloc((size_t)GH_ * INP_ * 2);      // OOB-read safe: ew0T follows
  u16* ew0T   = (u16*)alloc((size_t)NE_ * H_ * INP_ * 2);
  if (ws_size < off) return;

  // aliases (lifetime-checked):
  u16* D1 = A0;                                  // A0 dead after enc0
  u16* D2 = A1;                                  // A1 dead after enc1
  float* G1    = (float*)H2;                     // H2 dead after mu/lv
  float* COEFF = (float*)((char*)H2 + (size_t)B_ * GH_ * 4);
  u16* ew2T = (u16*)((char*)H2 + (size_t)4 * 1024 * 1024);   // transposed after mu/lv
  u16* ew1T = ZY;                                            // transposed after moe0

  float* outO = (float*)d_out;                       // [B,256]
  float* muO  = outO + (size_t)B_ * IN_;             // [B,128]
  float* lvO  = muO + (size_t)B_ * LAT_;             // [B,128]

  dim3 tb(32, 8);
  // weight transposes needed before the encoder/gating/moe0
  k_transpose<<<dim3(32, 48), tb, 0, stream>>>(enc_w0, encw0T, K0_, H_, 0, 0);
  k_transpose<<<dim3(32, 40), tb, 0, stream>>>(enc_w1, encw1T, K1_, H_, 0, 0);
  k_transpose<<<dim3(4, 32),  tb, 0, stream>>>(mu_w, mulvT, H_, LAT_, 0, 0);
  k_transpose<<<dim3(4, 32),  tb, 0, stream>>>(lv_w, mulvT + (size_t)LAT_ * H_, H_, LAT_, 0, 0);
  k_transpose<<<dim3(2, 36),  tb, 0, stream>>>(g_w0, gw0T, INP_, GH_, 0, 0);
  k_transpose<<<dim3(32, 36, NE_), tb, 0, stream>>>(exp_w0, ew0T, INP_, H_,
                                                    (long)INP_ * H_, (long)INP_ * H_);
  // concat buffers
  long npr = (long)B_ * K0_ + (long)B_ * IN_;
  k_prep<<<(int)((npr + 255) / 256), 256, 0, stream>>>(x, y, A0, A1);

  // encoder (dense, MREP=4: 128x128 tiles)
  k_gemm<4, false><<<dim3(B_ / 128, H_ / 128), 256, 0, stream>>>(A0, K0_, encw0T, 0, enc_b0,
      nullptr, H_, K0_, 1, A1, nullptr, nullptr, K1_, H_, nullptr, 1);
  k_gemm<4, false><<<dim3(B_ / 128, H_ / 128), 256, 0, stream>>>(A1, K1_, encw1T, 0, enc_b1,
      nullptr, H_, K1_, 1, H2, nullptr, nullptr, H_, H_, nullptr, 1);
  // mu / logvar (MREP=2: 64x128 tiles -> 256 blocks; f32 split into d_out)
  k_gemm<2, false><<<dim3(B_ / 64, 2), 256, 0, stream>>>(H2, H_, mulvT, 0, mu_b, nullptr,
      256, H_, 1, nullptr, muO, lvO, LAT_, LAT_, lv_b, 0);

  // exp_w2 transpose into freed H2 space (after mu/lv read H2)
  k_transpose<<<dim3(8, 36, NE_), tb, 0, stream>>>(exp_w2, ew2T, INP_, IN_,
                                                   (long)INP_ * IN_, (long)INP_ * IN_);
  // z + [z|y] assembly
  long nz = (long)B_ * INP_;
  k_z<<<(int)((nz + 255) / 256), 256, 0, stream>>>(muO, lvO, eps, y, ZY, D1, D2);

  // gating (MREP=2; N=64 < BN: B-tile OOB rows read into ew0T region, unused cols skipped)
  k_gemm<2, false><<<dim3(B_ / 64, 1), 256, 0, stream>>>(ZY, INP_, gw0T, 0, g_b0, nullptr,
      GH_, INP_, 1, nullptr, G1, nullptr, GH_, GH_, nullptr, 1);
  k_gate<<<B_ / 256, 256, 0, stream>>>(G1, g_w1, g_b1, g_w2, g_b2, COEFF);

  // decoder MoE layer 0: ZY -> D1[:,128:1152]
  k_gemm<4, true><<<dim3(B_ / 128, H_ / 128), 256, 0, stream>>>(ZY, INP_, ew0T, (long)H_ * INP_,
      exp_b0, COEFF, H_, INP_, NE_, D1 + LAT_, nullptr, nullptr, INP_, H_, nullptr, 1);
  // exp_w1 transpose into freed ZY space (after moe0 read ZY)
  k_transpose<<<dim3(32, 36, NE_), tb, 0, stream>>>(exp_w1, ew1T, INP_, H_,
                                                    (long)INP_ * H_, (long)INP_ * H_);
  // decoder MoE layer 1: D1 -> D2[:,128:1152]
  k_gemm<4, true><<<dim3(B_ / 128, H_ / 128), 256, 0, stream>>>(D1, INP_, ew1T, (long)H_ * INP_,
      exp_b1, COEFF, H_, INP_, NE_, D2 + LAT_, nullptr, nullptr, INP_, H_, nullptr, 1);
  // decoder MoE layer 2: D2 -> d_out [B,256] f32 (MREP=2 -> 256 blocks)
  k_gemm<2, true><<<dim3(B_ / 64, 2), 256, 0, stream>>>(D2, INP_, ew2T, (long)IN_ * INP_,
      exp_b2, COEFF, IN_, INP_, NE_, nullptr, outO, nullptr, IN_, IN_, nullptr, 0);
}

// Round 3
// 599.148 us; speedup vs baseline: 1.5721x; 1.2055x over previous
//
#include <hip/hip_runtime.h>
#include <hip/hip_bf16.h>
#include <cstddef>

using u16 = unsigned short;
using short8 = __attribute__((ext_vector_type(8))) short;
using f32x4 = __attribute__((ext_vector_type(4))) float;

constexpr int B_   = 8192;
constexpr int IN_  = 256;
constexpr int COND_= 1024;
constexpr int H_   = 1024;
constexpr int LAT_ = 128;
constexpr int NE_  = 6;
constexpr int GH_  = 64;
constexpr int INP_ = 1152;   // LAT+COND == LAT+H
constexpr int K0_  = 1536;   // IN+COND+IN
constexpr int K1_  = 1280;   // H+IN

constexpr int BK = 64;       // K-step (128 B per LDS row)

typedef const __attribute__((address_space(1))) void gv_t;
typedef __attribute__((address_space(3))) void lv_t;
#define GLDS(g, l) __builtin_amdgcn_global_load_lds((gv_t*)(g), (lv_t*)(l), 16, 0, 0)

__device__ __forceinline__ u16 f2b(float f) {
  __hip_bfloat16 h = __float2bfloat16(f);
  return *reinterpret_cast<u16*>(&h);
}
__device__ __forceinline__ float elu1(float x) { return x > 0.f ? x : (__expf(x) - 1.f); }

// ---------------- transpose + f32->bf16 convert: in [R][C] f32 -> out [C][R] bf16
__global__ void k_transpose(const float* __restrict__ in, u16* __restrict__ out,
                            int R, int C, long inStride, long outStride) {
  __shared__ float t[32][33];
  const float* ip = in + (long)blockIdx.z * inStride;
  u16* op = out + (long)blockIdx.z * outStride;
  int c0 = blockIdx.x * 32, r0 = blockIdx.y * 32;
  int tx = threadIdx.x, ty = threadIdx.y; // 32x8
#pragma unroll
  for (int i = 0; i < 4; i++) {
    int r = r0 + ty + i * 8, c = c0 + tx;
    if (r < R && c < C) t[ty + i * 8][tx] = ip[(long)r * C + c];
  }
  __syncthreads();
#pragma unroll
  for (int i = 0; i < 4; i++) {
    int c = c0 + ty + i * 8, r = r0 + tx;
    if (r < R && c < C) op[(long)c * R + r] = f2b(t[tx][ty + i * 8]);
  }
}

// ---------------- build A0 = [x|y|x] bf16 and A1 x-columns
__global__ void k_prep(const float* __restrict__ x, const float* __restrict__ y,
                       u16* __restrict__ A0, u16* __restrict__ A1) {
  long idx = (long)blockIdx.x * blockDim.x + threadIdx.x;
  long n0 = (long)B_ * K0_;
  if (idx < n0) {
    int b = (int)(idx / K0_), c = (int)(idx % K0_);
    float v;
    if (c < IN_)            v = x[(long)b * IN_ + c];
    else if (c < IN_+COND_) v = y[(long)b * COND_ + (c - IN_)];
    else                    v = x[(long)b * IN_ + (c - IN_ - COND_)];
    A0[idx] = f2b(v);
  } else {
    long j = idx - n0;
    if (j < (long)B_ * IN_) {
      int b = (int)(j / IN_), c = (int)(j % IN_);
      A1[(long)b * K1_ + H_ + c] = f2b(x[(long)b * IN_ + c]);
    }
  }
}

// ---------------- z = mu + eps*exp(0.5*lv); fill ZY=[z|y], z-cols of D1,D2
__global__ void k_z(const float* __restrict__ mu, const float* __restrict__ lv,
                    const float* __restrict__ eps, const float* __restrict__ y,
                    u16* __restrict__ ZY, u16* __restrict__ D1, u16* __restrict__ D2) {
  long idx = (long)blockIdx.x * blockDim.x + threadIdx.x;
  if (idx >= (long)B_ * INP_) return;
  int b = (int)(idx / INP_), c = (int)(idx % INP_);
  if (c < LAT_) {
    long o = (long)b * LAT_ + c;
    float z = mu[o] + eps[o] * __expf(0.5f * lv[o]);
    u16 zb = f2b(z);
    ZY[idx] = zb; D1[idx] = zb; D2[idx] = zb;
  } else {
    ZY[idx] = f2b(y[(long)b * COND_ + (c - LAT_)]);
  }
}

// ---------------- gating tail: g2 = elu(g1@w1+b1); logits = g2@w2+b2; softmax
__global__ __launch_bounds__(256) void k_gate(const float* __restrict__ G1,
    const float* __restrict__ w1, const float* __restrict__ b1,
    const float* __restrict__ w2, const float* __restrict__ b2,
    float* __restrict__ coeff) {
  __shared__ float W1[64][65];
  __shared__ float W2[64][8];
  __shared__ float B1[64], B2[8];
  int tid = threadIdx.x;
  for (int i = tid; i < 64 * 64; i += 256) W1[i >> 6][i & 63] = w1[i];
  for (int i = tid; i < 64 * 6; i += 256) W2[i / 6][i % 6] = w2[i];
  if (tid < 64) B1[tid] = b1[tid];
  if (tid < 8)  B2[tid] = (tid < 6) ? b2[tid] : 0.f;
  __syncthreads();
  int row = blockIdx.x * 256 + tid;
  const float* gr = G1 + (long)row * GH_;
  float g[64];
#pragma unroll
  for (int i = 0; i < 16; i++) {
    float4 v = *(const float4*)(gr + i * 4);
    g[i*4] = v.x; g[i*4+1] = v.y; g[i*4+2] = v.z; g[i*4+3] = v.w;
  }
  float lg[6];
#pragma unroll
  for (int e = 0; e < 6; e++) lg[e] = B2[e];
  for (int n = 0; n < 64; n++) {
    float s = B1[n];
#pragma unroll
    for (int k = 0; k < 64; k++) s += g[k] * W1[k][n];
    s = elu1(s);
#pragma unroll
    for (int e = 0; e < 6; e++) lg[e] += s * W2[n][e];
  }
  float m = lg[0];
#pragma unroll
  for (int e = 1; e < 6; e++) m = fmaxf(m, lg[e]);
  float p[6], sum = 0.f;
#pragma unroll
  for (int e = 0; e < 6; e++) { p[e] = __expf(lg[e] - m); sum += p[e]; }
  float inv = 1.f / sum;
#pragma unroll
  for (int e = 0; e < 6; e++) coeff[(long)row * 6 + e] = p[e] * inv;
}

// ---------------- MFMA GEMM (+MoE):
// m97 staging (global_load_lds w16) + double-buffered single-barrier pipeline
// + XOR-swizzled LDS via pre-swizzled GLOBAL source (rule #21):
//   stored[r][16B-block b] = orig[r][b ^ (r&7)]; reads XOR the same involution.
// WT: [E][N][K] bf16 (pre-transposed). coeff: [M][6] when MOE.
// BM = 32*MREP, BN = 128 fixed. 4 waves, per-wave (16*MREP) x 64 output.
template<int MREP, bool MOE>
__global__ __launch_bounds__(256, 2) void k_gemm(
    const u16* __restrict__ A, int lda,
    const u16* __restrict__ WT, long wstride,
    const float* __restrict__ bias,
    const float* __restrict__ coeff,
    int N, int K, int E,
    u16* __restrict__ outH, float* __restrict__ outF, float* __restrict__ outF2,
    int ldo, int splitcol, const float* __restrict__ bias2, int act)
{
  constexpr int BMt = 32 * MREP;
  __shared__ __align__(16) u16 As[2][BMt][BK];
  __shared__ __align__(16) u16 Bs[2][128][BK];
  __shared__ float Cf[MOE ? BMt : 1][8];

  const int tid = threadIdx.x;
  const int lane = tid & 63, w = tid >> 6;
  const int wr = w >> 1, wc = w & 1;
  const int brow = blockIdx.x * BMt, bcol = blockIdx.y * 128;
  const int lr = lane & 15, hi = lane >> 4;
  const int lk = hi * 8;
  const int xsw = (lr & 7) << 3;            // read-side swizzle (8-elem blocks)

  if (MOE && tid < BMt) {
#pragma unroll
    for (int e2 = 0; e2 < 8; e2++)
      Cf[tid][e2] = (e2 < 6) ? coeff[(long)(brow + tid) * 6 + e2] : 0.f;
  }

  f32x4 acc[MREP][4];
#pragma unroll
  for (int m = 0; m < MREP; m++)
#pragma unroll
    for (int n = 0; n < 4; n++)
#pragma unroll
      for (int r = 0; r < 4; r++) acc[m][n][r] = 0.f;

  // staging geometry: lane l -> row srow=(w*8)+(l>>3); LDS dest block l&7 (linear,
  // = wave base + lane*16); GLOBAL source block (l&7)^(srow&7)  => swizzled store.
  const int srow = w * 8 + (lane >> 3);
  const int sdst = (lane & 7) * 8;
  const int ssrc = ((lane & 7) ^ ((lane >> 3) & 7)) * 8;
  const u16* Asrc = A + (long)(brow + srow) * lda + ssrc;
  const u16* Bsrc = WT + (long)(bcol + srow) * K + ssrc;
  const int KSTEPS = K / BK;

  int cur = 0;
  // prologue: stage (e=0, kt=0) into buf 0
#pragma unroll
  for (int i = 0; i < BMt / 32; i++)
    GLDS(Asrc + (long)(i * 32) * lda, &As[0][i * 32 + srow][sdst]);
#pragma unroll
  for (int i = 0; i < 4; i++)
    GLDS(Bsrc + (long)(i * 32) * K, &Bs[0][i * 32 + srow][sdst]);

  for (int e = 0; e < E; ++e) {
    f32x4 pacc[MREP][4];
    if constexpr (MOE) {
#pragma unroll
      for (int m = 0; m < MREP; m++)
#pragma unroll
        for (int n = 0; n < 4; n++)
#pragma unroll
          for (int r = 0; r < 4; r++) pacc[m][n][r] = 0.f;
    }

    for (int kt = 0; kt < KSTEPS; ++kt) {
      __syncthreads();   // drains this tile's loads; all waves done reading buf being restaged
      // issue NEXT tile's loads into the other buffer (flies under compute below)
      int ne = e, nk = kt + 1;
      if (nk == KSTEPS) { nk = 0; ne = e + 1; }
      if (ne < E) {
        const u16* ap = Asrc + (long)nk * BK;
        const u16* bp = Bsrc + (long)ne * wstride + (long)nk * BK;
#pragma unroll
        for (int i = 0; i < BMt / 32; i++)
          GLDS(ap + (long)(i * 32) * lda, &As[cur ^ 1][i * 32 + srow][sdst]);
#pragma unroll
        for (int i = 0; i < 4; i++)
          GLDS(bp + (long)(i * 32) * K, &Bs[cur ^ 1][i * 32 + srow][sdst]);
      }
      // compute current tile
#pragma unroll
      for (int kk = 0; kk < BK; kk += 32) {
        short8 af[MREP], bfr[4];
        const int cc = (kk + lk) ^ xsw;
#pragma unroll
        for (int m = 0; m < MREP; m++)
          af[m] = *(const short8*)&As[cur][wr * (16 * MREP) + m * 16 + lr][cc];
#pragma unroll
        for (int n = 0; n < 4; n++)
          bfr[n] = *(const short8*)&Bs[cur][wc * 64 + n * 16 + lr][cc];
#pragma unroll
        for (int m = 0; m < MREP; m++)
#pragma unroll
          for (int n = 0; n < 4; n++) {
            if constexpr (MOE)
              pacc[m][n] = __builtin_amdgcn_mfma_f32_16x16x32_bf16(af[m], bfr[n], pacc[m][n], 0, 0, 0);
            else
              acc[m][n] = __builtin_amdgcn_mfma_f32_16x16x32_bf16(af[m], bfr[n], acc[m][n], 0, 0, 0);
          }
      }
      cur ^= 1;
    }
    if constexpr (MOE) {
#pragma unroll
      for (int m = 0; m < MREP; m++)
#pragma unroll
        for (int r = 0; r < 4; r++) {
          float c = Cf[wr * (16 * MREP) + m * 16 + hi * 4 + r][e];
#pragma unroll
          for (int n = 0; n < 4; n++) acc[m][n][r] += c * pacc[m][n][r];
        }
    }
  }

  // epilogue
#pragma unroll
  for (int m = 0; m < MREP; m++)
#pragma unroll
    for (int n = 0; n < 4; n++) {
      int col = bcol + wc * 64 + n * 16 + lr;
      if (col >= N) continue;
#pragma unroll
      for (int r = 0; r < 4; r++) {
        int rowl = wr * (16 * MREP) + m * 16 + hi * 4 + r;
        long row = brow + rowl;
        float v = acc[m][n][r];
        if constexpr (MOE) {
          float bv = 0.f;
#pragma unroll
          for (int e = 0; e < 6; e++) bv += Cf[rowl][e] * bias[(long)e * N + col];
          v += bv;
        } else {
          v += (col < splitcol) ? bias[col] : bias2[col - splitcol];
        }
        if (act) v = elu1(v);
        if (outH) outH[row * ldo + col] = f2b(v);
        else if (col < splitcol) outF[row * ldo + col] = v;
        else outF2[row * ldo + (col - splitcol)] = v;
      }
    }
}

extern "C" void kernel_launch(void* const* d_in, const int* in_sizes, int n_in,
                              void* d_out, int out_size, void* d_ws, size_t ws_size,
                              hipStream_t stream) {
  (void)in_sizes; (void)out_size;
  if (n_in < 23) return;
  const float* x      = (const float*)d_in[0];
  const float* y      = (const float*)d_in[1];
  const float* eps    = (const float*)d_in[2];
  const float* enc_w0 = (const float*)d_in[3];
  const float* enc_b0 = (const float*)d_in[4];
  const float* enc_w1 = (const float*)d_in[5];
  const float* enc_b1 = (const float*)d_in[6];
  const float* mu_w   = (const float*)d_in[7];
  const float* mu_b   = (const float*)d_in[8];
  const float* lv_w   = (const float*)d_in[9];
  const float* lv_b   = (const float*)d_in[10];
  const float* g_w0   = (const float*)d_in[11];
  const float* g_b0   = (const float*)d_in[12];
  const float* g_w1   = (const float*)d_in[13];
  const float* g_b1   = (const float*)d_in[14];
  const float* g_w2   = (const float*)d_in[15];
  const float* g_b2   = (const float*)d_in[16];
  const float* exp_w0 = (const float*)d_in[17];
  const float* exp_b0 = (const float*)d_in[18];
  const float* exp_w1 = (const float*)d_in[19];
  const float* exp_b1 = (const float*)d_in[20];
  const float* exp_w2 = (const float*)d_in[21];
  const float* exp_b2 = (const float*)d_in[22];

  char* ws = (char*)d_ws;
  size_t off = 0;
  auto alloc = [&](size_t bytes) -> void* {
    void* p = ws + off; off += (bytes + 255) & ~(size_t)255; return p;
  };
  u16* A0     = (u16*)alloc((size_t)B_ * K0_ * 2);        // enc0 input [x|y|x]; later D1
  u16* A1     = (u16*)alloc((size_t)B_ * K1_ * 2);        // enc1 input [h1|x]; later D2
  u16* H2     = (u16*)alloc((size_t)B_ * H_ * 2);         // enc2 output; later G1/COEFF/ew2T
  u16* ZY     = (u16*)alloc((size_t)B_ * INP_ * 2);       // [z|y]; later ew1T
  u16* encw0T = (u16*)alloc((size_t)K0_ * H_ * 2);
  u16* encw1T = (u16*)alloc((size_t)K1_ * H_ * 2);
  u16* mulvT  = (u16*)alloc((size_t)256 * H_ * 2);
  u16* gw0T   = (u16*)alloc((size_t)GH_ * INP_ * 2);      // OOB-read safe: ew0T follows
  u16* ew0T   = (u16*)alloc((size_t)NE_ * H_ * INP_ * 2);
  if (ws_size < off) return;

  // aliases (lifetime-checked):
  u16* D1 = A0;                                  // A0 dead after enc0
  u16* D2 = A1;                                  // A1 dead after enc1
  float* G1    = (float*)H2;                     // H2 dead after mu/lv
  float* COEFF = (float*)((char*)H2 + (size_t)B_ * GH_ * 4);
  u16* ew2T = (u16*)((char*)H2 + (size_t)4 * 1024 * 1024);   // transposed after mu/lv
  u16* ew1T = ZY;                                            // transposed after moe0

  float* outO = (float*)d_out;                       // [B,256]
  float* muO  = outO + (size_t)B_ * IN_;             // [B,128]
  float* lvO  = muO + (size_t)B_ * LAT_;             // [B,128]

  dim3 tb(32, 8);
  // weight transposes needed before the encoder/gating/moe0
  k_transpose<<<dim3(32, 48), tb, 0, stream>>>(enc_w0, encw0T, K0_, H_, 0, 0);
  k_transpose<<<dim3(32, 40), tb, 0, stream>>>(enc_w1, encw1T, K1_, H_, 0, 0);
  k_transpose<<<dim3(4, 32),  tb, 0, stream>>>(mu_w, mulvT, H_, LAT_, 0, 0);
  k_transpose<<<dim3(4, 32),  tb, 0, stream>>>(lv_w, mulvT + (size_t)LAT_ * H_, H_, LAT_, 0, 0);
  k_transpose<<<dim3(2, 36),  tb, 0, stream>>>(g_w0, gw0T, INP_, GH_, 0, 0);
  k_transpose<<<dim3(32, 36, NE_), tb, 0, stream>>>(exp_w0, ew0T, INP_, H_,
                                                    (long)INP_ * H_, (long)INP_ * H_);
  // concat buffers
  long npr = (long)B_ * K0_ + (long)B_ * IN_;
  k_prep<<<(int)((npr + 255) / 256), 256, 0, stream>>>(x, y, A0, A1);

  // encoder (dense, MREP=4: 128x128 tiles)
  k_gemm<4, false><<<dim3(B_ / 128, H_ / 128), 256, 0, stream>>>(A0, K0_, encw0T, 0, enc_b0,
      nullptr, H_, K0_, 1, A1, nullptr, nullptr, K1_, H_, nullptr, 1);
  k_gemm<4, false><<<dim3(B_ / 128, H_ / 128), 256, 0, stream>>>(A1, K1_, encw1T, 0, enc_b1,
      nullptr, H_, K1_, 1, H2, nullptr, nullptr, H_, H_, nullptr, 1);
  // mu / logvar (MREP=2: 64x128 tiles -> 256 blocks; f32 split into d_out)
  k_gemm<2, false><<<dim3(B_ / 64, 2), 256, 0, stream>>>(H2, H_, mulvT, 0, mu_b, nullptr,
      256, H_, 1, nullptr, muO, lvO, LAT_, LAT_, lv_b, 0);

  // exp_w2 transpose into freed H2 space (after mu/lv read H2)
  k_transpose<<<dim3(8, 36, NE_), tb, 0, stream>>>(exp_w2, ew2T, INP_, IN_,
                                                   (long)INP_ * IN_, (long)INP_ * IN_);
  // z + [z|y] assembly
  long nz = (long)B_ * INP_;
  k_z<<<(int)((nz + 255) / 256), 256, 0, stream>>>(muO, lvO, eps, y, ZY, D1, D2);

  // gating (MREP=2; N=64 < BN: B-tile OOB rows read into ew0T region, unused cols skipped)
  k_gemm<2, false><<<dim3(B_ / 64, 1), 256, 0, stream>>>(ZY, INP_, gw0T, 0, g_b0, nullptr,
      GH_, INP_, 1, nullptr, G1, nullptr, GH_, GH_, nullptr, 1);
  k_gate<<<B_ / 256, 256, 0, stream>>>(G1, g_w1, g_b1, g_w2, g_b2, COEFF);

  // decoder MoE layer 0: ZY -> D1[:,128:1152]
  k_gemm<4, true><<<dim3(B_ / 128, H_ / 128), 256, 0, stream>>>(ZY, INP_, ew0T, (long)H_ * INP_,
      exp_b0, COEFF, H_, INP_, NE_, D1 + LAT_, nullptr, nullptr, INP_, H_, nullptr, 1);
  // exp_w1 transpose into freed ZY space (after moe0 read ZY)
  k_transpose<<<dim3(32, 36, NE_), tb, 0, stream>>>(exp_w1, ew1T, INP_, H_,
                                                    (long)INP_ * H_, (long)INP_ * H_);
  // decoder MoE layer 1: D1 -> D2[:,128:1152]
  k_gemm<4, true><<<dim3(B_ / 128, H_ / 128), 256, 0, stream>>>(D1, INP_, ew1T, (long)H_ * INP_,
      exp_b1, COEFF, H_, INP_, NE_, D2 + LAT_, nullptr, nullptr, INP_, H_, nullptr, 1);
  // decoder MoE layer 2: D2 -> d_out [B,256] f32 (MREP=2 -> 256 blocks)
  k_gemm<2, true><<<dim3(B_ / 64, 2), 256, 0, stream>>>(D2, INP_, ew2T, (long)IN_ * INP_,
      exp_b2, COEFF, IN_, INP_, NE_, nullptr, outO, nullptr, IN_, IN_, nullptr, 0);
}